// Round 1
// baseline (193.159 us; speedup 1.0000x reference)
//
#include <hip/hip_runtime.h>
#include <math.h>

// Problem constants (from reference): 20 qubits, B=16 batch, RX chain on qubit 0,
// 2-qubit Hamiltonian evolution on qubits (2,5), observable = sum_q Z_q.
// State layout: (dim, B) row-major => flat idx = i*B + b; qubit q bit of i is at
// bit position (19 - q). So qubit 0 -> bit 19, qubit 2 -> bit 17, qubit 5 -> bit 14.
constexpr int NQ     = 20;
constexpr int DIM    = 1 << NQ;
constexpr int B      = 16;
constexpr int GROUPS = 1 << 17;   // DIM / 8 (octets over bits 19,17,14)
constexpr int NBLK   = 1024;
constexpr int NTHR   = 256;

// ws layout (floats):
//   [0..15]    cos(0.5*sum theta) per batch
//   [16..31]   sin(0.5*sum theta) per batch
//   [32..543]  Ue per batch: b*32 + (i*4+j)*2 (+1 imag)
//   [544..]    per-block partials: NBLK*16 floats

// ---- Prep: composed RX coefficients + exp(-i t H) via fp64 scaling-squaring ----
__global__ void prep_kernel(const float* __restrict__ hre, const float* __restrict__ him,
                            const float* __restrict__ theta, const float* __restrict__ tv,
                            float* __restrict__ ws) {
  int b = threadIdx.x;
  if (b >= B) return;

  // All RX on the same qubit commute: product = RX(sum theta).
  double th = 0.0;
  for (int k = 0; k < 8; k++) th += (double)theta[k * B + b];
  th *= 0.5;
  ws[b]     = (float)cos(th);
  ws[B + b] = (float)sin(th);

  // H = 0.5*(A + A^H);  M = -i * t * H  =>  Mre = t*Him, Mim = -t*Hre
  double t = (double)tv[b];
  double Mre[4][4], Mim[4][4];
  for (int i = 0; i < 4; i++)
    for (int j = 0; j < 4; j++) {
      double are = hre[(i*4+j)*B + b], aim = him[(i*4+j)*B + b];
      double cre = hre[(j*4+i)*B + b], cim = him[(j*4+i)*B + b];
      double Hre = 0.5*(are + cre), Him = 0.5*(aim - cim);
      Mre[i][j] = t * Him;
      Mim[i][j] = -t * Hre;
    }

  // Scaling: inf-norm upper bound, halve until <= 0.25
  double ninf = 0.0;
  for (int i = 0; i < 4; i++) {
    double r = 0.0;
    for (int j = 0; j < 4; j++) r += fabs(Mre[i][j]) + fabs(Mim[i][j]);
    ninf = fmax(ninf, r);
  }
  int sc = 0;
  while (ninf > 0.25 && sc < 40) { ninf *= 0.5; sc++; }
  double scale = ldexp(1.0, -sc);
  for (int i = 0; i < 4; i++)
    for (int j = 0; j < 4; j++) { Mre[i][j] *= scale; Mim[i][j] *= scale; }

  // Taylor via Horner: T = I; for k=K..1: T = I + M*T/k
  double Tre[4][4], Tim[4][4];
  for (int i = 0; i < 4; i++)
    for (int j = 0; j < 4; j++) { Tre[i][j] = (i==j) ? 1.0 : 0.0; Tim[i][j] = 0.0; }
  for (int k = 13; k >= 1; k--) {
    double Pre[4][4], Pim[4][4];
    double inv = 1.0 / (double)k;
    for (int i = 0; i < 4; i++)
      for (int j = 0; j < 4; j++) {
        double rr = 0.0, ii = 0.0;
        for (int m = 0; m < 4; m++) {
          rr += Mre[i][m]*Tre[m][j] - Mim[i][m]*Tim[m][j];
          ii += Mre[i][m]*Tim[m][j] + Mim[i][m]*Tre[m][j];
        }
        Pre[i][j] = rr*inv + ((i==j) ? 1.0 : 0.0);
        Pim[i][j] = ii*inv;
      }
    for (int i = 0; i < 4; i++)
      for (int j = 0; j < 4; j++) { Tre[i][j] = Pre[i][j]; Tim[i][j] = Pim[i][j]; }
  }
  // Squaring
  for (int q = 0; q < sc; q++) {
    double Pre[4][4], Pim[4][4];
    for (int i = 0; i < 4; i++)
      for (int j = 0; j < 4; j++) {
        double rr = 0.0, ii = 0.0;
        for (int m = 0; m < 4; m++) {
          rr += Tre[i][m]*Tre[m][j] - Tim[i][m]*Tim[m][j];
          ii += Tre[i][m]*Tim[m][j] + Tim[i][m]*Tre[m][j];
        }
        Pre[i][j] = rr; Pim[i][j] = ii;
      }
    for (int i = 0; i < 4; i++)
      for (int j = 0; j < 4; j++) { Tre[i][j] = Pre[i][j]; Tim[i][j] = Pim[i][j]; }
  }

  float* ue = ws + 2*B + b*32;
  for (int i = 0; i < 4; i++)
    for (int j = 0; j < 4; j++) {
      ue[(i*4+j)*2]     = (float)Tre[i][j];
      ue[(i*4+j)*2 + 1] = (float)Tim[i][j];
    }
}

// ---- Fused gate-apply + expectation. Never materializes the post-gate state. ----
__global__ __launch_bounds__(NTHR) void fused_kernel(
    const float* __restrict__ sre, const float* __restrict__ sim,
    const float* __restrict__ ws, float* __restrict__ partial) {
  int tid = blockIdx.x * NTHR + threadIdx.x;
  int b = tid & 15;

  float c = ws[b], s = ws[B + b];
  float ur[4][4], ui[4][4];
  {
    const float* ue = ws + 2*B + b*32;
    #pragma unroll
    for (int i = 0; i < 4; i++)
      #pragma unroll
      for (int j = 0; j < 4; j++) { ur[i][j] = ue[(i*4+j)*2]; ui[i][j] = ue[(i*4+j)*2+1]; }
  }

  float acc = 0.f;
  const int total = NBLK * NTHR;           // multiple of 16 => b stays fixed
  for (int u = tid; u < GROUPS * 16; u += total) {
    int g = u >> 4;
    // expand 17-bit group id into 20-bit base with bits 14,17,19 zero
    int base = (g & 0x3FFF) | ((g & 0xC000) << 1) | ((g & 0x10000) << 2);
    int a0 = base * B + b;

    float ar[8], ai[8];
    #pragma unroll
    for (int j = 0; j < 8; j++) {
      int off = a0 + (((((j>>2)&1) << 19) | (((j>>1)&1) << 17) | ((j&1) << 14))) * B;
      ar[j] = sre[off];
      ai[j] = sim[off];
    }

    // RX(theta_sum) on qubit 0 (bit j>>2): pairs (j, j+4); -i*s*(x) = s*xi - i*s*xr
    #pragma unroll
    for (int j = 0; j < 4; j++) {
      float xr = ar[j], xi = ai[j], yr = ar[j+4], yi = ai[j+4];
      ar[j]   = c*xr + s*yi;   ai[j]   = c*xi - s*yr;
      ar[j+4] = s*xi + c*yr;   ai[j+4] = c*yi - s*xr;
    }

    // Ue on (qubit2,qubit5) = (bit1,bit0 of k); weight folded in immediately
    int pc = __popc(base);
    float wb = (float)(17 - 2*pc);
    #pragma unroll
    for (int h = 0; h < 2; h++) {
      float w0 = wb + (h ? -1.f : 1.f);
      #pragma unroll
      for (int k = 0; k < 4; k++) {
        float rr = 0.f, ii = 0.f;
        #pragma unroll
        for (int m = 0; m < 4; m++) {
          float xr = ar[h*4+m], xi = ai[h*4+m];
          rr = fmaf(ur[k][m], xr, rr); rr = fmaf(-ui[k][m], xi, rr);
          ii = fmaf(ur[k][m], xi, ii); ii = fmaf(ui[k][m], xr, ii);
        }
        int sb = ((k>>1)&1) + (k&1);
        float w = w0 + (float)(2 - 2*sb);
        acc = fmaf(rr*rr + ii*ii, w, acc);
      }
    }
  }

  // lanes {l, l^16, l^32, l^48} share b => butterfly over bits 4,5
  acc += __shfl_xor(acc, 16, 64);
  acc += __shfl_xor(acc, 32, 64);

  __shared__ float red[16];
  if (threadIdx.x < 16) red[threadIdx.x] = 0.f;
  __syncthreads();
  if ((threadIdx.x & 63) < 16) atomicAdd(&red[threadIdx.x & 15], acc);
  __syncthreads();
  if (threadIdx.x < 16) partial[blockIdx.x * 16 + threadIdx.x] = red[threadIdx.x];
}

// ---- Final reduction over per-block partials ----
__global__ void reduce_kernel(const float* __restrict__ partial, float* __restrict__ out) {
  int t = threadIdx.x;       // 256 threads
  int b = t & 15;
  float acc = 0.f;
  for (int i = t >> 4; i < NBLK; i += 16)
    acc += partial[i * 16 + b];
  acc += __shfl_xor(acc, 16, 64);
  acc += __shfl_xor(acc, 32, 64);
  __shared__ float red[16];
  if (t < 16) red[t] = 0.f;
  __syncthreads();
  if ((t & 63) < 16) atomicAdd(&red[t & 15], acc);
  __syncthreads();
  if (t < 16) out[t] = red[t];
}

extern "C" void kernel_launch(void* const* d_in, const int* in_sizes, int n_in,
                              void* d_out, int out_size, void* d_ws, size_t ws_size,
                              hipStream_t stream) {
  const float* sre = (const float*)d_in[0];
  const float* sim = (const float*)d_in[1];
  const float* hre = (const float*)d_in[2];
  const float* him = (const float*)d_in[3];
  const float* th  = (const float*)d_in[4];
  const float* tv  = (const float*)d_in[5];

  float* ws = (float*)d_ws;
  float* partial = ws + 544;

  prep_kernel<<<1, 64, 0, stream>>>(hre, him, th, tv, ws);
  fused_kernel<<<NBLK, NTHR, 0, stream>>>(sre, sim, ws, partial);
  reduce_kernel<<<1, 256, 0, stream>>>(partial, (float*)d_out);
}